// Round 4
// baseline (363.250 us; speedup 1.0000x reference)
//
#include <hip/hip_runtime.h>
#include <stdint.h>

// out[b,o,m] = sum_i in[b,i,m] * w[i,o,m]  (complex, fp32)
// B=32, Ci=Co=128, M=64*65=4160. One float2 per complex element.
//
// Block: MPB=4 modes, full 32b x 128o. 512 thr = [worker s:7][mode ml:2];
// worker tile 8b x 4o (64 VGPR acc, v_pk_fma_f32 complex MACs).
// Staging: global_load_lds dwordx4, double-buffered LDS (2 x 20KB).
// T3/T4 pipeline: raw s_barrier + COUNTED vmcnt (never 0 in main loop) --
// chunk c+1's DMA stays in flight across both barriers; iter c waits only
// for its own chunk-c load group (3 loads waves 0-3, 2 loads waves 4-7).
// W tile XOR-swizzled both sides (pre-swizzled global src + swizzled
// ds_read) -> 0 bank conflicts (verified R3).

typedef float f2 __attribute__((ext_vector_type(2)));

#define NB 32
#define CI 128
#define CO 128
#define MODES 4160
#define MPB 4
#define KC 4
#define NCHUNK (CI / KC)
#define ABUF_F2 (KC * NB * MPB)       // 512 f2  = 4 KB
#define WBUF_F2 (KC * CO * MPB)       // 2048 f2 = 16 KB
#define BUF_F2  (ABUF_F2 + WBUF_F2)   // 20 KB per buffer

// acc.lo += a.lo*w.lo - a.hi*w.hi ; acc.hi += a.lo*w.hi + a.hi*w.lo
#define CFMA(acc, av, wv)                                                      \
  asm("v_pk_fma_f32 %0, %1, %2, %0 op_sel:[0,0,0] op_sel_hi:[0,1,1]"           \
      : "+v"(acc) : "v"(av), "v"(wv));                                         \
  asm("v_pk_fma_f32 %0, %1, %2, %0 op_sel:[1,1,0] op_sel_hi:[1,0,1] "          \
      "neg_lo:[1,0,0]"                                                         \
      : "+v"(acc) : "v"(av), "v"(wv));

#define VM_WAIT(N) asm volatile("s_waitcnt vmcnt(" #N ")" ::: "memory")

__device__ __forceinline__ void gload16(const f2* g, f2* l) {
    __builtin_amdgcn_global_load_lds(
        (const __attribute__((address_space(1))) uint32_t*)g,
        (__attribute__((address_space(3))) uint32_t*)l, 16, 0, 0);
}

// Stage one K-chunk (KC=4) into dst. Linear LDS order = DMA lane order.
// A: unit t (0..255): kk=t>>6, b=(t>>1)&31, ml0=(t&1)*2  (no swizzle).
// W: unit j (0..1023): logical o recovered from the inverse of
//    phys = (kk*4096 + o*32 + ml*8) ^ (((o>>2)&3)<<5).
// Waves 0-3 issue 3 loads/chunk, waves 4-7 issue 2 (wave-uniform split).
__device__ __forceinline__ void stage_chunk(const f2* __restrict__ Ig,
                                            const f2* __restrict__ Wl,
                                            f2* dst, int t, int m0, int k0) {
    if (t < 256) {
        const int kk = t >> 6, b = (t >> 1) & 31, ml0 = (t & 1) << 1;
        gload16(Ig + (size_t)(b * CI + k0 + kk) * MODES + m0 + ml0,
                dst + t * 2);
    }
#pragma unroll
    for (int p = 0; p < 2; ++p) {
        const int j  = p * 512 + t;
        const int jj = j & 255, kk = j >> 8;
        const int ohi = jj >> 3;
        const int o   = (ohi << 2) | (((jj >> 1) & 3) ^ (ohi & 3));
        const int ml0 = (jj & 1) << 1;
        gload16(Wl + (size_t)((k0 + kk) * CO + o) * MODES + m0 + ml0,
                dst + ABUF_F2 + j * 2);
    }
}

__global__ __launch_bounds__(512, 4)
void cmul2d_kernel(const f2* __restrict__ Ig,
                   const f2* __restrict__ Wl,
                   f2* __restrict__ Og) {
    __shared__ f2 lds[2 * BUF_F2];   // 40 KB

    const int t = threadIdx.x;

    // pair-preserving XCD swizzle (mode-quad pairs of one 64B line -> same L2)
    const int bid  = blockIdx.x;
    const int x    = bid & 7;
    const int half = (bid >> 3) & 1;
    const int kq   = bid >> 4;
    const int m0   = (((kq << 3) + x) * 2 + half) * MPB;

    const int ml = t & 3;
    const int s  = t >> 2;
    const int so = s & 31;
    const int sb = s >> 5;

    // swizzled effective o-rows for W ds_reads (matches staging XOR)
    int oe[4];
#pragma unroll
    for (int q = 0; q < 4; ++q)
        oe[q] = ((so << 2) | q) ^ (so & 3);

    f2 acc[8][4];
#pragma unroll
    for (int r = 0; r < 8; ++r)
#pragma unroll
        for (int q = 0; q < 4; ++q) acc[r][q] = (f2)(0.0f);

    // prologue: fill both pipeline stages
    stage_chunk(Ig, Wl, lds,          t, m0, 0);
    stage_chunk(Ig, Wl, lds + BUF_F2, t, m0, KC);

#pragma unroll 1
    for (int c = 0; c < NCHUNK; ++c) {
        // wait ONLY for chunk c's own load group; c+1 stays in flight
        if (c + 1 < NCHUNK) {
            if (t < 256) { VM_WAIT(3); } else { VM_WAIT(2); }
        } else {
            VM_WAIT(0);
        }
        __builtin_amdgcn_s_barrier();       // all waves: chunk c landed
        __builtin_amdgcn_sched_barrier(0);

        const f2* Ab = lds + (c & 1) * BUF_F2;
        const f2* Wb = Ab + ABUF_F2;
#pragma unroll
        for (int kk = 0; kk < KC; ++kk) {
            f2 a[8], w[4];
#pragma unroll
            for (int r = 0; r < 8; ++r)
                a[r] = Ab[kk * (NB * MPB) + (sb * 8 + r) * MPB + ml];
#pragma unroll
            for (int q = 0; q < 4; ++q)
                w[q] = Wb[kk * (CO * MPB) + oe[q] * MPB + ml];
#pragma unroll
            for (int r = 0; r < 8; ++r)
#pragma unroll
                for (int q = 0; q < 4; ++q) {
                    CFMA(acc[r][q], a[r], w[q]);
                }
        }

        __builtin_amdgcn_sched_barrier(0);
        __builtin_amdgcn_s_barrier();       // all waves done reading buf c&1
        if (c + 2 < NCHUNK)                 // refill just-freed buffer
            stage_chunk(Ig, Wl, lds + (c & 1) * BUF_F2, t, m0, (c + 2) * KC);
    }

    // epilogue: one f2 store per element; 4-lane mode groups = 32B segments
#pragma unroll
    for (int r = 0; r < 8; ++r) {
        const int b = sb * 8 + r;
#pragma unroll
        for (int q = 0; q < 4; ++q) {
            const int o = so * 4 + q;
            Og[(size_t)(b * CO + o) * MODES + m0 + ml] = acc[r][q];
        }
    }
}

extern "C" void kernel_launch(void* const* d_in, const int* in_sizes, int n_in,
                              void* d_out, int out_size, void* d_ws, size_t ws_size,
                              hipStream_t stream) {
    const f2* I = (const f2*)d_in[0];
    const f2* W = (const f2*)d_in[1];
    f2* O = (f2*)d_out;
    dim3 grid(MODES / MPB);   // 1040
    dim3 block(512);
    cmul2d_kernel<<<grid, block, 0, stream>>>(I, W, O);
}

// Round 5
// 261.669 us; speedup vs baseline: 1.3882x; 1.3882x over previous
//
#include <hip/hip_runtime.h>
#include <stdint.h>

// out[b,o,m] = sum_i in[b,i,m] * w[i,o,m]  (complex, fp32)
// B=32, Ci=Co=128, M=64*65=4160. One float2 per complex element.
//
// R5: 64B DRAM granules. Block = 32b x 64o x 8 modes (o-half), 512 thr,
// grid 1040. Per (row, k) the DMA reads 8 modes * 8B = 64B contiguous ->
// full DRAM bursts (R4's 32B granules capped HBM at 2.3 TB/s).
// Thread tile 4b x 8o (64 f2 acc -> ~114 combined regs, 4 waves/SIMD,
// 2 blocks/CU). DMA: global_load_lds dwordx4, double-buffered 2x24KB,
// counted vmcnt (uniform 3 loads/thread/chunk). W rows XOR-swizzled
// (bit0 ^= bit3, both sides) -> 2-way (free) LDS reads.
// Half-pair blocks mapped to the same XCD so I's second read hits L2.

typedef float f2 __attribute__((ext_vector_type(2)));

#define NB 32
#define CI 128
#define CO 128
#define OT 64
#define MODES 4160
#define MPB 8
#define KC 4
#define NCHUNK (CI / KC)
#define ABUF_F2 (KC * NB * MPB)        // 1024 f2 =  8 KB
#define WBUF_F2 (KC * OT * MPB)        // 2048 f2 = 16 KB
#define BUF_F2  (ABUF_F2 + WBUF_F2)    // 24 KB per buffer

// acc.lo += a.lo*w.lo - a.hi*w.hi ; acc.hi += a.lo*w.hi + a.hi*w.lo
#define CFMA(acc, av, wv)                                                      \
  asm("v_pk_fma_f32 %0, %1, %2, %0 op_sel:[0,0,0] op_sel_hi:[0,1,1]"           \
      : "+v"(acc) : "v"(av), "v"(wv));                                         \
  asm("v_pk_fma_f32 %0, %1, %2, %0 op_sel:[1,1,0] op_sel_hi:[1,0,1] "          \
      "neg_lo:[1,0,0]"                                                         \
      : "+v"(acc) : "v"(av), "v"(wv));

#define VM_WAIT(N) asm volatile("s_waitcnt vmcnt(" #N ")" ::: "memory")

__device__ __forceinline__ void gload16(const f2* g, f2* l) {
    __builtin_amdgcn_global_load_lds(
        (const __attribute__((address_space(1))) uint32_t*)g,
        (__attribute__((address_space(3))) uint32_t*)l, 16, 0, 0);
}

// Stage one K-chunk (KC=4). 3 x 16B DMA per thread (uniform).
// A (512 units): slot t <-> (kk=t>>7, b=(t>>2)&31, mlq=t&3), linear layout.
// W (1024 units): slot j <-> (kk=j>>8, op=(j>>2)&63, mlq=j&3); slot op holds
//   logical o = op ^ ((op>>3)&1)  (involution; read side applies same XOR).
__device__ __forceinline__ void stage_chunk(const f2* __restrict__ Ig,
                                            const f2* __restrict__ Wl,
                                            f2* dst, int t, int m0,
                                            int obase, int k0) {
    {
        const int kk = t >> 7, b = (t >> 2) & 31, ml0 = (t & 3) << 1;
        gload16(Ig + (size_t)(b * CI + k0 + kk) * MODES + m0 + ml0,
                dst + t * 2);
    }
#pragma unroll
    for (int p = 0; p < 2; ++p) {
        const int j  = p * 512 + t;
        const int kk = j >> 8, op = (j >> 2) & 63, ml0 = (j & 3) << 1;
        const int o  = op ^ ((op >> 3) & 1);
        gload16(Wl + (size_t)((k0 + kk) * CO + obase + o) * MODES + m0 + ml0,
                dst + ABUF_F2 + j * 2);
    }
}

__global__ __launch_bounds__(512, 4)
void cmul2d_kernel(const f2* __restrict__ Ig,
                   const f2* __restrict__ Wl,
                   f2* __restrict__ Og) {
    __shared__ f2 lds[2 * BUF_F2];   // 48 KB -> 2 blocks/CU

    const int t = threadIdx.x;

    // XCD-chunked job map (1040 = 8 XCDs x 130). jid pairs (2k,2k+1) = the
    // two o-halves of one mode-octet -> adjacent in one XCD's run -> I's
    // second read is an L2 hit.
    const int bid = blockIdx.x;
    const int jid = (bid & 7) * 130 + (bid >> 3);
    const int m0    = (jid >> 1) * MPB;
    const int obase = (jid & 1) * OT;

    const int ml = t & 7;      // mode lane (coalesced epilogue)
    const int s  = t >> 3;     // worker 0..63
    const int so = s & 7;      // o-group (8 o each)
    const int sb = s >> 3;     // b-group (4 b each) -- wave-uniform

    f2 acc[4][8];
#pragma unroll
    for (int r = 0; r < 4; ++r)
#pragma unroll
        for (int q = 0; q < 8; ++q) acc[r][q] = (f2)(0.0f);

    // prologue: fill both pipeline stages (6 loads in flight / thread)
    stage_chunk(Ig, Wl, lds,          t, m0, obase, 0);
    stage_chunk(Ig, Wl, lds + BUF_F2, t, m0, obase, KC);

#pragma unroll 1
    for (int c = 0; c < NCHUNK; ++c) {
        // wait only for chunk c's 3 loads; chunk c+1 stays in flight
        if (c < NCHUNK - 1) { VM_WAIT(3); } else { VM_WAIT(0); }
        __builtin_amdgcn_s_barrier();        // chunk c landed for all waves
        __builtin_amdgcn_sched_barrier(0);

        const f2* Ab = lds + (c & 1) * BUF_F2;
        const f2* Wb = Ab + ABUF_F2;
#pragma unroll
        for (int kk = 0; kk < KC; ++kk) {
            f2 a[4], w[8];
#pragma unroll
            for (int r = 0; r < 4; ++r)          // one row, 8 ml: broadcast
                a[r] = Ab[(kk * NB + sb * 4 + r) * MPB + ml];
#pragma unroll
            for (int q = 0; q < 8; ++q) {        // swizzled row: 2-way, free
                const int o  = so * 8 + q;
                const int op = o ^ ((o >> 3) & 1);
                w[q] = Wb[(kk * OT + op) * MPB + ml];
            }
#pragma unroll
            for (int r = 0; r < 4; ++r)
#pragma unroll
                for (int q = 0; q < 8; ++q) {
                    CFMA(acc[r][q], a[r], w[q]);
                }
        }

        __builtin_amdgcn_sched_barrier(0);
        __builtin_amdgcn_s_barrier();        // all waves done reading buf c&1
        if (c + 2 < NCHUNK)                  // refill just-freed buffer
            stage_chunk(Ig, Wl, lds + (c & 1) * BUF_F2, t, m0, obase,
                        (c + 2) * KC);
    }

    // epilogue: per (b,o) the 8 ml lanes are consecutive -> 64B stores
#pragma unroll
    for (int r = 0; r < 4; ++r) {
        const int b = sb * 4 + r;
#pragma unroll
        for (int q = 0; q < 8; ++q) {
            const int o = obase + so * 8 + q;
            Og[(size_t)(b * CO + o) * MODES + m0 + ml] = acc[r][q];
        }
    }
}

extern "C" void kernel_launch(void* const* d_in, const int* in_sizes, int n_in,
                              void* d_out, int out_size, void* d_ws, size_t ws_size,
                              hipStream_t stream) {
    const f2* I = (const f2*)d_in[0];
    const f2* W = (const f2*)d_in[1];
    f2* O = (f2*)d_out;
    dim3 grid(1040);   // 520 mode-octets x 2 o-halves
    dim3 block(512);
    cmul2d_kernel<<<grid, block, 0, stream>>>(I, W, O);
}